// Round 4
// baseline (3616.023 us; speedup 1.0000x reference)
//
#include <hip/hip_runtime.h>
#include <stdint.h>

// GRU fused persistent kernel, MI355X gfx950 — round 12.
// History: r8 3.47ms (MALL sc1 flags) | r9 FAIL (plain buffer_inv = CU NOP) |
// r10 11.9ms (per-poll buffer_inv sc1 = catastrophic) | r11 2.64ms WIN:
// nt-load polling, XCD-local L2 exchange (WRITE 147MB->2.3MB signature).
// r11 residual: 6200cy/step; ~2/3 is hop overhead: per round
// store->drain(300)->flag(200)->flagpoll(250)->slab(250), x2 rounds, plus
// X(t) HBM fetch serialized inside the phase-A poll's vmcnt(0), plus
// max-of-16 WG jitter.
//
// r12 = TAGGED-PAYLOAD exchange + X prefetch + ah-move:
//  - Exchange elements widen to 8B {payload, step_tag}, written by ONE
//    global_store_dwordx2 (8B in one L2 sector -> pair-atomic visibility).
//    Producer: store pairs, NO drain, NO flag, proceed. Consumer: poll the
//    slab itself until ALL 16 tags == target (per-element check -> no
//    cross-element store-ordering assumption). Round hop ~250cy vs ~1000.
//  - Overwrite safety (single-slot h and rh): writer of h(t+1) passed its
//    phase-B(t) tag-join on rh(t) from ALL WGs (union over 8 waves = all
//    16); any WG publishes rh(t) only after its phase-A barrier, i.e.
//    after its h(t) slab reads RETURNED. So h(t+1) stores happen-after all
//    h(t) reads. Same chain (shifted) protects rh. Tags are exact (==),
//    never ahead: a producer can't reach step t+1's stores without the
//    t-join that includes every consumer's successful t-read.
//  - X/mask prefetch: issue X(t+1)+mask(t+1) loads right after the phase-B
//    slab returns; latency hides under phase-B MFMA/epilogue/next-poll
//    instead of being eaten by the phase-A poll's vmcnt(0).
//  - ah (x@Wh) MFMAs move from phase A to the rh-exchange shadow.
//  - Census+smoke unchanged (r10/r11 hardware-proven). tagL gate host-side
//    on ws_size: tagged layout 545KB; smaller ws -> exact r11 compact path.
//    Census/smoke fail in tagged mode -> same tag protocol over sc1/MALL
//    (tags still sync; just slower hops). All spins budget-bounded.
//
// tagged ws (dwords): hbT[8][8][1024] pairs = 65536 | rhbT[8][8][1024] =
// 65536 | (flags kept for layout compat) 8192 | cns 160 = 139424 dw = 545KB.

#define GT    512
#define GDIN  512
#define GDOUT 512
#define NGRP  8
#define NSL   16
#define GROWS 8
#define COLS  32
#define NWAVE 8
#define KW    64
#define NWG   (NGRP * NSL)                          // 128

#define FLSTR 4
#define FLGRP (NSL * NWAVE * FLSTR)                 // 512 dw per group

// tagged layout (dwords)
#define T_OFF_HB   0                                // [8][8][1024] pairs
#define T_OFF_RHB  (NGRP * GROWS * 1024)            // 65536
#define T_OFF_HFL  (T_OFF_RHB + NGRP * GROWS * 1024)// 131072 (unused, compat)
#define T_OFF_RFL  (T_OFF_HFL + NGRP * FLGRP)       // 135168
#define T_OFF_CNS  (T_OFF_RFL + NGRP * FLGRP)       // 139264
#define T_INIT_DW  (T_OFF_CNS + 160)                // 139424 dw = 545KB

// compact layout (exact r11)
#define C_OFF_HB   0                                // [2][8][8][512]
#define C_OFF_RHB  (2 * NGRP * GROWS * 512)         // 65536
#define C_OFF_HFL  (C_OFF_RHB + NGRP * GROWS * 512) // 98304
#define C_OFF_RFL  (C_OFF_HFL + NGRP * FLGRP)       // 102400
#define C_OFF_CNS  (C_OFF_RFL + NGRP * FLGRP)       // 106496
#define C_INIT_DW  (C_OFF_CNS + 160)                // 106656 dw = 427KB

typedef __attribute__((ext_vector_type(8))) short bf16x8;
typedef __attribute__((ext_vector_type(4))) float f32x4;
typedef __attribute__((ext_vector_type(4))) unsigned int u32x4;
typedef __attribute__((ext_vector_type(2))) unsigned int u32x2;

__device__ __forceinline__ short f2bf(float f) {
  union { float f; uint32_t u; } v; v.f = f;
  uint32_t r = (v.u + 0x7FFFu + ((v.u >> 16) & 1u)) >> 16;  // RNE
  return (short)(uint16_t)r;
}
__device__ __forceinline__ float bf2f(short s) {
  union { uint32_t u; float f; } v; v.u = ((uint32_t)(uint16_t)s) << 16;
  return v.f;
}
__device__ __forceinline__ uint32_t pack_hl(float v) {
  short hi = f2bf(v);
  short lo = f2bf(v - bf2f(hi));
  return ((uint32_t)(uint16_t)hi << 16) | (uint32_t)(uint16_t)lo;
}

__device__ __forceinline__ void st_sc1(uint32_t* p, uint32_t v) {
  asm volatile("global_store_dword %0, %1, off sc1" :: "v"(p), "v"(v) : "memory");
}
__device__ __forceinline__ void st_pl(uint32_t* p, uint32_t v) {
  asm volatile("global_store_dword %0, %1, off" :: "v"(p), "v"(v) : "memory");
}
// pair store: ONE dwordx2 -> payload+tag visible atomically (8B, one sector)
__device__ __forceinline__ void st2(uint32_t* p, uint32_t pay, uint32_t tag, int fast) {
  u32x2 v; v[0] = pay; v[1] = tag;
  if (fast)
    asm volatile("global_store_dwordx2 %0, %1, off" :: "v"(p), "v"(v) : "memory");
  else
    asm volatile("global_store_dwordx2 %0, %1, off sc1" :: "v"(p), "v"(v) : "memory");
}
__device__ __forceinline__ void vm_drain() {
  asm volatile("s_waitcnt vmcnt(0)" ::: "memory");
}
__device__ __forceinline__ void l1_inv() {   // one-time hygiene only
  asm volatile("buffer_inv sc1" ::: "memory");
}
__device__ __forceinline__ uint32_t ld_nt(const uint32_t* p) {
  uint32_t v;
  asm volatile("global_load_dword %0, %1, off nt\n\ts_waitcnt vmcnt(0)"
               : "=v"(v) : "v"(p) : "memory");
  return v;
}

// ---- tagged-pair slab: 8x dwordx4 = 16 pairs (2 k-subtiles) ----
__device__ __forceinline__ void slab8p(const uint32_t* base, u32x4 d[8], int fast) {
  if (fast) {
    asm volatile(
      "global_load_dwordx4 %0, %8, off nt\n\t"
      "global_load_dwordx4 %1, %8, off offset:16 nt\n\t"
      "global_load_dwordx4 %2, %8, off offset:32 nt\n\t"
      "global_load_dwordx4 %3, %8, off offset:48 nt\n\t"
      "global_load_dwordx4 %4, %8, off offset:256 nt\n\t"
      "global_load_dwordx4 %5, %8, off offset:272 nt\n\t"
      "global_load_dwordx4 %6, %8, off offset:288 nt\n\t"
      "global_load_dwordx4 %7, %8, off offset:304 nt\n\t"
      "s_waitcnt vmcnt(0)"
      : "=&v"(d[0]), "=&v"(d[1]), "=&v"(d[2]), "=&v"(d[3]),
        "=&v"(d[4]), "=&v"(d[5]), "=&v"(d[6]), "=&v"(d[7])
      : "v"(base) : "memory");
  } else {
    asm volatile(
      "global_load_dwordx4 %0, %8, off sc1\n\t"
      "global_load_dwordx4 %1, %8, off offset:16 sc1\n\t"
      "global_load_dwordx4 %2, %8, off offset:32 sc1\n\t"
      "global_load_dwordx4 %3, %8, off offset:48 sc1\n\t"
      "global_load_dwordx4 %4, %8, off offset:256 sc1\n\t"
      "global_load_dwordx4 %5, %8, off offset:272 sc1\n\t"
      "global_load_dwordx4 %6, %8, off offset:288 sc1\n\t"
      "global_load_dwordx4 %7, %8, off offset:304 sc1\n\t"
      "s_waitcnt vmcnt(0)"
      : "=&v"(d[0]), "=&v"(d[1]), "=&v"(d[2]), "=&v"(d[3]),
        "=&v"(d[4]), "=&v"(d[5]), "=&v"(d[6]), "=&v"(d[7])
      : "v"(base) : "memory");
  }
}
// retry until all 16 tags == tgt (check=0: single load, no tag check)
__device__ __forceinline__ void slabp_wait(const uint32_t* base, uint32_t tgt,
                                           u32x4 d[8], int check, int fast,
                                           int& budget) {
  for (;;) {
    slab8p(base, d, fast);
    if (!check) return;
    uint32_t x = (d[0][1]^tgt)|(d[0][3]^tgt)|(d[1][1]^tgt)|(d[1][3]^tgt)
               | (d[2][1]^tgt)|(d[2][3]^tgt)|(d[3][1]^tgt)|(d[3][3]^tgt)
               | (d[4][1]^tgt)|(d[4][3]^tgt)|(d[5][1]^tgt)|(d[5][3]^tgt)
               | (d[6][1]^tgt)|(d[6][3]^tgt)|(d[7][1]^tgt)|(d[7][3]^tgt);
    if (__all((int)(x == 0u))) return;
    if (--budget <= 0) return;
  }
}

// ---- compact (r11) primitives ----
__device__ __forceinline__ void slab4_sc1(const uint32_t* base, u32x4 d[4]) {
  asm volatile(
    "global_load_dwordx4 %0, %4, off sc1\n\t"
    "global_load_dwordx4 %1, %4, off offset:16 sc1\n\t"
    "global_load_dwordx4 %2, %4, off offset:128 sc1\n\t"
    "global_load_dwordx4 %3, %4, off offset:144 sc1\n\t"
    "s_waitcnt vmcnt(0)"
    : "=&v"(d[0]), "=&v"(d[1]), "=&v"(d[2]), "=&v"(d[3])
    : "v"(base) : "memory");
}
__device__ __forceinline__ void slab4_nt(const uint32_t* base, u32x4 d[4]) {
  asm volatile(
    "global_load_dwordx4 %0, %4, off nt\n\t"
    "global_load_dwordx4 %1, %4, off offset:16 nt\n\t"
    "global_load_dwordx4 %2, %4, off offset:128 nt\n\t"
    "global_load_dwordx4 %3, %4, off offset:144 nt\n\t"
    "s_waitcnt vmcnt(0)"
    : "=&v"(d[0]), "=&v"(d[1]), "=&v"(d[2]), "=&v"(d[3])
    : "v"(base) : "memory");
}
__device__ __forceinline__ void wait16(const uint32_t* fbase, uint32_t tgt,
                                       int lane, int wv, int fast, int& budget) {
  if (budget <= 0) return;
  const int idx = lane & 15;
  const uint32_t* p = fbase +
      (size_t)(((2 * wv + (idx >> 3)) * NWAVE + (idx & 7)) * FLSTR);
  if (fast) {
    for (;;) {
      uint32_t v = ld_nt(p);
      if (__all((int)(v >= tgt))) break;
      if (--budget <= 0) break;
    }
  } else {
    for (;;) {
      uint32_t v = __hip_atomic_load(p, __ATOMIC_RELAXED, __HIP_MEMORY_SCOPE_AGENT);
      if (__all((int)(v >= tgt))) break;
      if (--budget <= 0) break;
    }
  }
  asm volatile("" ::: "memory");
}

union U16x8 { uint32_t u[4]; bf16x8 v; };
__device__ __forceinline__ void mk_frags(const u32x4 A, const u32x4 B,
                                         bf16x8& hi, bf16x8& lo) {
  U16x8 h, l;
  h.u[0] = (A[0] >> 16) | (A[1] & 0xFFFF0000u);  l.u[0] = (A[0] & 0xFFFFu) | (A[1] << 16);
  h.u[1] = (A[2] >> 16) | (A[3] & 0xFFFF0000u);  l.u[1] = (A[2] & 0xFFFFu) | (A[3] << 16);
  h.u[2] = (B[0] >> 16) | (B[1] & 0xFFFF0000u);  l.u[2] = (B[0] & 0xFFFFu) | (B[1] << 16);
  h.u[3] = (B[2] >> 16) | (B[3] & 0xFFFF0000u);  l.u[3] = (B[2] & 0xFFFFu) | (B[3] << 16);
  hi = h.v; lo = l.v;
}

__global__ __launch_bounds__(512, 2)
void gru_fused(const float* __restrict__ X, const int* __restrict__ mask,
               const float* __restrict__ Wz, const float* __restrict__ Uz,
               const float* __restrict__ bz,
               const float* __restrict__ Wr, const float* __restrict__ Ur,
               const float* __restrict__ br,
               const float* __restrict__ Wh, const float* __restrict__ Uh,
               const float* __restrict__ bh,
               float* __restrict__ out, uint32_t* __restrict__ ws, int tagL)
{
  const int tid   = threadIdx.x;
  const int wv    = tid >> 6;
  const int lane  = tid & 63;
  const int col16 = lane & 15;
  const int quad  = lane >> 4;
  const int row8  = lane & 7;

  // ---- census (assignment) + smoke test (fast/slow selection) ----
  uint32_t* cns = ws + (tagL ? T_OFF_CNS : C_OFF_CNS);
  __shared__ int s_mode, s_g, s_sl;
  if (tid == 0) {
    uint32_t xcc = 0;
    asm volatile("s_getreg_b32 %0, hwreg(HW_REG_XCC_ID)" : "=s"(xcc));
    xcc &= 7u;
    uint32_t slot = __hip_atomic_fetch_add(&cns[xcc], 1u, __ATOMIC_RELAXED,
                                           __HIP_MEMORY_SCOPE_AGENT);
    if (slot >= (uint32_t)NSL)
      __hip_atomic_fetch_add(&cns[9], 1u, __ATOMIC_RELAXED, __HIP_MEMORY_SCOPE_AGENT);
    __hip_atomic_fetch_add(&cns[8], 1u, __ATOMIC_RELEASE, __HIP_MEMORY_SCOPE_AGENT);
    uint32_t tv = 0; long sp = 0;
    do {
      tv = __hip_atomic_load(&cns[8], __ATOMIC_ACQUIRE, __HIP_MEMORY_SCOPE_AGENT);
    } while (tv < (uint32_t)NWG && ++sp < 2000000L);
    uint32_t bad = __hip_atomic_load(&cns[9], __ATOMIC_RELAXED, __HIP_MEMORY_SCOPE_AGENT);
    const int cok = (tv >= (uint32_t)NWG && bad == 0u);
    int g_, sl_, mode_ = 0;
    if (cok) {
      g_ = (int)xcc; sl_ = (int)slot;
      l1_inv();
      uint32_t* tok = cns + 16;
      st_pl(&tok[g_ * NSL + sl_], 1u);
      vm_drain();
      const uint32_t* np = &tok[g_ * NSL + ((sl_ + 1) & (NSL - 1))];
      int ok = 0;
      for (long i = 0; i < 300000L; ++i) {
        if (ld_nt(np) != 0u) { ok = 1; break; }
      }
      if (!ok)
        __hip_atomic_fetch_add(&cns[11], 1u, __ATOMIC_RELAXED, __HIP_MEMORY_SCOPE_AGENT);
      __hip_atomic_fetch_add(&cns[10], 1u, __ATOMIC_RELEASE, __HIP_MEMORY_SCOPE_AGENT);
      uint32_t tv2 = 0; sp = 0;
      do {
        tv2 = __hip_atomic_load(&cns[10], __ATOMIC_ACQUIRE, __HIP_MEMORY_SCOPE_AGENT);
      } while (tv2 < (uint32_t)NWG && ++sp < 2000000L);
      uint32_t fl = __hip_atomic_load(&cns[11], __ATOMIC_RELAXED, __HIP_MEMORY_SCOPE_AGENT);
      mode_ = (tv2 >= (uint32_t)NWG && fl == 0u) ? 1 : 0;
    } else {
      g_ = (int)(blockIdx.x & 7); sl_ = (int)(blockIdx.x >> 3);
    }
    s_mode = mode_; s_g = g_; s_sl = sl_;
  }
  __syncthreads();
  const int fast = __builtin_amdgcn_readfirstlane(s_mode);
  const int g    = __builtin_amdgcn_readfirstlane(s_g);
  const int sl   = __builtin_amdgcn_readfirstlane(s_sl);
  l1_inv();                            // one-time: clear cross-launch vL1

  const int jb = sl * COLS;
  const int kb = wv * KW;

  __shared__ __align__(16) float scrA[2][NWAVE][2][GROWS][COLS];
  __shared__ __align__(16) float scrB[2][NWAVE][GROWS][COLS];

  // ---------- one-time: weight B-fragments into registers ----------
  bf16x8 uzh[2][2], uzl[2][2], urh[2][2], url[2][2], uhh[2][2], uhl[2][2];
  bf16x8 wzf[2][2], wrf[2][2], whf[2][2];
#pragma unroll
  for (int c = 0; c < 2; ++c) {
#pragma unroll
    for (int Tt = 0; Tt < 2; ++Tt) {
      const int k0 = kb + c * 32 + quad * 8;
      const int j  = jb + Tt * 16 + col16;
      bf16x8 t_uzh, t_uzl, t_urh, t_url, t_uhh, t_uhl, t_wz, t_wr, t_wh;
#pragma unroll
      for (int i = 0; i < 8; ++i) {
        const int idx = (k0 + i) * GDOUT + j;
        float u; short hi;
        u = Uz[idx]; hi = f2bf(u); t_uzh[i] = hi; t_uzl[i] = f2bf(u - bf2f(hi));
        u = Ur[idx]; hi = f2bf(u); t_urh[i] = hi; t_url[i] = f2bf(u - bf2f(hi));
        u = Uh[idx]; hi = f2bf(u); t_uhh[i] = hi; t_uhl[i] = f2bf(u - bf2f(hi));
        t_wz[i] = f2bf(Wz[idx]);
        t_wr[i] = f2bf(Wr[idx]);
        t_wh[i] = f2bf(Wh[idx]);
      }
      uzh[c][Tt] = t_uzh; uzl[c][Tt] = t_uzl; urh[c][Tt] = t_urh; url[c][Tt] = t_url;
      uhh[c][Tt] = t_uhh; uhl[c][Tt] = t_uhl;
      wzf[c][Tt] = t_wz;  wrf[c][Tt] = t_wr;  whf[c][Tt] = t_wh;
    }
  }

  const int ecol = lane & 31;
  const float bzv = bz[jb + ecol];
  const float brv = br[jb + ecol];
  const float bhv = bh[jb + ecol];
  const int b_ep = GROWS * g + wv;

  float hreg = 0.f;
  float zvl  = 0.f;
  int budget = 4000000;

  // ---- X/mask prefetch registers (t = 0) ----
  f32x4 xpA[2], xpB[2]; int mkpre;
  {
    const float* xr = X + (size_t)(GROWS * g + row8) * GT * GDIN;
#pragma unroll
    for (int c = 0; c < 2; ++c) {
      const float* xp = xr + (size_t)0 * GDIN + kb + c * 32 + quad * 8;
      xpA[c] = *(const f32x4*)xp;
      xpB[c] = *(const f32x4*)(xp + 4);
    }
    mkpre = mask[(size_t)b_ep * GT + 0];
  }

  if (tagL) {
    // ================= TAGGED-PAYLOAD PROTOCOL =================
    uint32_t* hbg = ws + T_OFF_HB  + (size_t)g * GROWS * 1024;
    uint32_t* rhg = ws + T_OFF_RHB + (size_t)g * GROWS * 1024;
    const int slab2 = row8 * 1024 + 2 * (kb + quad * 8);

    for (int t = 0; t < GT; ++t) {
      const int par = t & 1;
      // xa from prefetched regs (no vmem on the critical path)
      bf16x8 xa[2];
#pragma unroll
      for (int c = 0; c < 2; ++c) {
        bf16x8 xf;
#pragma unroll
        for (int i = 0; i < 4; ++i) { xf[i] = f2bf(xpA[c][i]); xf[i + 4] = f2bf(xpB[c][i]); }
        xa[c] = xf;
      }
      const int mk = mkpre;

      // ---- phase A: tag-poll h(t) slab, frags, 32 MFMAs (z, r) ----
      u32x4 hd[8];
      slabp_wait(hbg + slab2, (uint32_t)t, hd, t != 0, fast, budget);

      f32x4 az[2]  = {{0,0,0,0},{0,0,0,0}}, az2[2] = {{0,0,0,0},{0,0,0,0}};
      f32x4 ar[2]  = {{0,0,0,0},{0,0,0,0}}, ar2[2] = {{0,0,0,0},{0,0,0,0}};
#pragma unroll
      for (int c = 0; c < 2; ++c) {
        u32x4 A; A[0]=hd[4*c][0]; A[1]=hd[4*c][2]; A[2]=hd[4*c+1][0]; A[3]=hd[4*c+1][2];
        u32x4 B; B[0]=hd[4*c+2][0]; B[1]=hd[4*c+2][2]; B[2]=hd[4*c+3][0]; B[3]=hd[4*c+3][2];
        bf16x8 hhi, hlo;
        mk_frags(A, B, hhi, hlo);
#pragma unroll
        for (int Tt = 0; Tt < 2; ++Tt) {
          az[Tt]  = __builtin_amdgcn_mfma_f32_16x16x32_bf16(hhi, uzh[c][Tt], az[Tt],  0, 0, 0);
          az2[Tt] = __builtin_amdgcn_mfma_f32_16x16x32_bf16(hlo, uzh[c][Tt], az2[Tt], 0, 0, 0);
          az[Tt]  = __builtin_amdgcn_mfma_f32_16x16x32_bf16(hhi, uzl[c][Tt], az[Tt],  0, 0, 0);
          az2[Tt] = __builtin_amdgcn_mfma_f32_16x16x32_bf16(xa[c], wzf[c][Tt], az2[Tt], 0, 0, 0);
          ar[Tt]  = __builtin_amdgcn_mfma_f32_16x16x32_bf16(hhi, urh[c][Tt], ar[Tt],  0, 0, 0);
          ar2[Tt] = __builtin_amdgcn_mfma_f32_16x16x32_bf16(hlo, urh[c][Tt], ar2[Tt], 0, 0, 0);
          ar[Tt]  = __builtin_amdgcn_mfma_f32_16x16x32_bf16(hhi, url[c][Tt], ar[Tt],  0, 0, 0);
          ar2[Tt] = __builtin_amdgcn_mfma_f32_16x16x32_bf16(xa[c], wrf[c][Tt], ar2[Tt], 0, 0, 0);
        }
      }

      if (quad < 2) {
#pragma unroll
        for (int Tt = 0; Tt < 2; ++Tt)
#pragma unroll
          for (int rr = 0; rr < 4; ++rr) {
            scrA[par][wv][0][quad * 4 + rr][Tt * 16 + col16] = az[Tt][rr] + az2[Tt][rr];
            scrA[par][wv][1][quad * 4 + rr][Tt * 16 + col16] = ar[Tt][rr] + ar2[Tt][rr];
          }
      }
      __syncthreads();                   // all-8 join (tag-union = all 16 WGs)

      float zsum = 0.f, rsum = 0.f;
#pragma unroll
      for (int w2 = 0; w2 < NWAVE; ++w2) {
        zsum += scrA[par][w2][0][wv][ecol];
        rsum += scrA[par][w2][1][wv][ecol];
      }
      zvl = 1.f / (1.f + __expf(-(zsum + bzv)));
      const float rvl = 1.f / (1.f + __expf(-(rsum + brv)));
      if (lane < 32)
        st2(rhg + (size_t)wv * 1024 + (size_t)(jb + lane) * 2,
            pack_hl(rvl * hreg), (uint32_t)(t + 1), fast);
      // NO drain, NO flag — tags carry the sync.

      // ah MFMAs hidden in the rh exchange shadow
      f32x4 ah[2] = {{0,0,0,0},{0,0,0,0}};
#pragma unroll
      for (int c = 0; c < 2; ++c)
#pragma unroll
        for (int Tt = 0; Tt < 2; ++Tt)
          ah[Tt] = __builtin_amdgcn_mfma_f32_16x16x32_bf16(xa[c], whf[c][Tt], ah[Tt], 0, 0, 0);

      // ---- phase B: tag-poll rh(t), 12 MFMAs (hh) ----
      u32x4 rd[8];
      slabp_wait(rhg + slab2, (uint32_t)(t + 1), rd, 1, fast, budget);

      // prefetch X(t+1)/mask(t+1): hides under MFMA B + epilogue + next poll
      {
        const int tn = (t + 1 < GT) ? t + 1 : t;
        const float* xr = X + (size_t)(GROWS * g + row8) * GT * GDIN;
#pragma unroll
        for (int c = 0; c < 2; ++c) {
          const float* xp = xr + (size_t)tn * GDIN + kb + c * 32 + quad * 8;
          xpA[c] = *(const f32x4*)xp;
          xpB[c] = *(const f32x4*)(xp + 4);
        }
        mkpre = mask[(size_t)b_ep * GT + tn];
      }

      f32x4 b1[2] = {{0,0,0,0},{0,0,0,0}}, b2[2] = {{0,0,0,0},{0,0,0,0}};
      f32x4 b3[2] = {{0,0,0,0},{0,0,0,0}};
#pragma unroll
      for (int c = 0; c < 2; ++c) {
        u32x4 A; A[0]=rd[4*c][0]; A[1]=rd[4*c][2]; A[2]=rd[4*c+1][0]; A[3]=rd[4*c+1][2];
        u32x4 B; B[0]=rd[4*c+2][0]; B[1]=rd[4*c+2][2]; B[2]=rd[4*c+3][0]; B[3]=rd[4*c+3][2];
        bf16x8 th, tl;
        mk_frags(A, B, th, tl);
#pragma unroll
        for (int Tt = 0; Tt < 2; ++Tt) {
          b1[Tt] = __builtin_amdgcn_mfma_f32_16x16x32_bf16(th, uhh[c][Tt], b1[Tt], 0, 0, 0);
          b2[Tt] = __builtin_amdgcn_mfma_f32_16x16x32_bf16(tl, uhh[c][Tt], b2[Tt], 0, 0, 0);
          b3[Tt] = __builtin_amdgcn_mfma_f32_16x16x32_bf16(th, uhl[c][Tt], b3[Tt], 0, 0, 0);
        }
      }

      if (quad < 2) {
#pragma unroll
        for (int Tt = 0; Tt < 2; ++Tt)
#pragma unroll
          for (int rr = 0; rr < 4; ++rr)
            scrB[par][wv][quad * 4 + rr][Tt * 16 + col16] =
                ah[Tt][rr] + b1[Tt][rr] + b2[Tt][rr] + b3[Tt][rr];
      }
      __syncthreads();                   // all-8 join (tag-union = all 16 WGs)

      float hsum = 0.f;
#pragma unroll
      for (int w2 = 0; w2 < NWAVE; ++w2) hsum += scrB[par][w2][wv][ecol];
      const float pre = hsum + bhv;
      const float e  = __expf(2.f * pre);
      const float hh = 1.f - 2.f / (e + 1.f);
      float hn = zvl * hreg + (1.f - zvl) * hh;
      hn = (mk > 0) ? hn : hreg;
      hreg = hn;

      if (lane < 32) {
        st2(hbg + (size_t)wv * 1024 + (size_t)(jb + lane) * 2,
            pack_hl(hn), (uint32_t)(t + 1), fast);
        if (t == GT - 1) out[(size_t)b_ep * GDOUT + jb + lane] = hn;
      }
      // NO drain, NO flag.
    }
  } else {
    // ================= COMPACT FLAG PROTOCOL (r11) =================
    uint32_t* hb  = ws + C_OFF_HB;
    uint32_t* rhb = ws + C_OFF_RHB;
    uint32_t* hfl = ws + C_OFF_HFL + (size_t)g * FLGRP;
    uint32_t* rfl = ws + C_OFF_RFL + (size_t)g * FLGRP;
    uint32_t* hfl_my = hfl + (size_t)(sl * NWAVE + wv) * FLSTR;
    uint32_t* rfl_my = rfl + (size_t)(sl * NWAVE + wv) * FLSTR;
    uint32_t* rhg = rhb + (size_t)g * (GROWS * GDOUT);
    const int slab_off = row8 * GDOUT + kb + quad * 8;

    for (int t = 0; t < GT; ++t) {
      const int par = t & 1;
      bf16x8 xa[2];
#pragma unroll
      for (int c = 0; c < 2; ++c) {
        bf16x8 xf;
#pragma unroll
        for (int i = 0; i < 4; ++i) { xf[i] = f2bf(xpA[c][i]); xf[i + 4] = f2bf(xpB[c][i]); }
        xa[c] = xf;
      }
      const int mk = mkpre;

      if (t) wait16(hfl, (uint32_t)t, lane, wv, fast, budget);
      const uint32_t* hsrc = hb + ((size_t)par * NGRP + g) * (GROWS * GDOUT) + slab_off;
      u32x4 hd[4];
      if (fast) slab4_nt(hsrc, hd); else slab4_sc1(hsrc, hd);

      f32x4 az[2]  = {{0,0,0,0},{0,0,0,0}}, az2[2] = {{0,0,0,0},{0,0,0,0}};
      f32x4 ar[2]  = {{0,0,0,0},{0,0,0,0}}, ar2[2] = {{0,0,0,0},{0,0,0,0}};
#pragma unroll
      for (int c = 0; c < 2; ++c) {
        bf16x8 hhi, hlo;
        mk_frags(hd[2 * c], hd[2 * c + 1], hhi, hlo);
#pragma unroll
        for (int Tt = 0; Tt < 2; ++Tt) {
          az[Tt]  = __builtin_amdgcn_mfma_f32_16x16x32_bf16(hhi, uzh[c][Tt], az[Tt],  0, 0, 0);
          az2[Tt] = __builtin_amdgcn_mfma_f32_16x16x32_bf16(hlo, uzh[c][Tt], az2[Tt], 0, 0, 0);
          az[Tt]  = __builtin_amdgcn_mfma_f32_16x16x32_bf16(hhi, uzl[c][Tt], az[Tt],  0, 0, 0);
          az2[Tt] = __builtin_amdgcn_mfma_f32_16x16x32_bf16(xa[c], wzf[c][Tt], az2[Tt], 0, 0, 0);
          ar[Tt]  = __builtin_amdgcn_mfma_f32_16x16x32_bf16(hhi, urh[c][Tt], ar[Tt],  0, 0, 0);
          ar2[Tt] = __builtin_amdgcn_mfma_f32_16x16x32_bf16(hlo, urh[c][Tt], ar2[Tt], 0, 0, 0);
          ar[Tt]  = __builtin_amdgcn_mfma_f32_16x16x32_bf16(hhi, url[c][Tt], ar[Tt],  0, 0, 0);
          ar2[Tt] = __builtin_amdgcn_mfma_f32_16x16x32_bf16(xa[c], wrf[c][Tt], ar2[Tt], 0, 0, 0);
        }
      }

      if (quad < 2) {
#pragma unroll
        for (int Tt = 0; Tt < 2; ++Tt)
#pragma unroll
          for (int rr = 0; rr < 4; ++rr) {
            scrA[par][wv][0][quad * 4 + rr][Tt * 16 + col16] = az[Tt][rr] + az2[Tt][rr];
            scrA[par][wv][1][quad * 4 + rr][Tt * 16 + col16] = ar[Tt][rr] + ar2[Tt][rr];
          }
      }
      __syncthreads();

      float zsum = 0.f, rsum = 0.f;
#pragma unroll
      for (int w2 = 0; w2 < NWAVE; ++w2) {
        zsum += scrA[par][w2][0][wv][ecol];
        rsum += scrA[par][w2][1][wv][ecol];
      }
      zvl = 1.f / (1.f + __expf(-(zsum + bzv)));
      const float rvl = 1.f / (1.f + __expf(-(rsum + brv)));
      if (lane < 32) {
        uint32_t* dst = rhg + (size_t)wv * GDOUT + jb + lane;
        const uint32_t pv = pack_hl(rvl * hreg);
        if (fast) st_pl(dst, pv); else st_sc1(dst, pv);
      }
      vm_drain();
      if (lane == 0) {
        if (fast) st_pl(rfl_my, (uint32_t)(t + 1)); else st_sc1(rfl_my, (uint32_t)(t + 1));
      }

      f32x4 ah[2] = {{0,0,0,0},{0,0,0,0}};
#pragma unroll
      for (int c = 0; c < 2; ++c)
#pragma unroll
        for (int Tt = 0; Tt < 2; ++Tt)
          ah[Tt] = __builtin_amdgcn_mfma_f32_16x16x32_bf16(xa[c], whf[c][Tt], ah[Tt], 0, 0, 0);

      wait16(rfl, (uint32_t)(t + 1), lane, wv, fast, budget);
      u32x4 rd[4];
      const uint32_t* rsrc = rhg + slab_off;
      if (fast) slab4_nt(rsrc, rd); else slab4_sc1(rsrc, rd);

      {
        const int tn = (t + 1 < GT) ? t + 1 : t;
        const float* xr = X + (size_t)(GROWS * g + row8) * GT * GDIN;
#pragma unroll
        for (int c = 0; c < 2; ++c) {
          const float* xp = xr + (size_t)tn * GDIN + kb + c * 32 + quad * 8;
          xpA[c] = *(const f32x4*)xp;
          xpB[c] = *(const f32x4*)(xp + 4);
        }
        mkpre = mask[(size_t)b_ep * GT + tn];
      }

      f32x4 b1[2] = {{0,0,0,0},{0,0,0,0}}, b2[2] = {{0,0,0,0},{0,0,0,0}};
      f32x4 b3[2] = {{0,0,0,0},{0,0,0,0}};
#pragma unroll
      for (int c = 0; c < 2; ++c) {
        bf16x8 th, tl;
        mk_frags(rd[2 * c], rd[2 * c + 1], th, tl);
#pragma unroll
        for (int Tt = 0; Tt < 2; ++Tt) {
          b1[Tt] = __builtin_amdgcn_mfma_f32_16x16x32_bf16(th, uhh[c][Tt], b1[Tt], 0, 0, 0);
          b2[Tt] = __builtin_amdgcn_mfma_f32_16x16x32_bf16(tl, uhh[c][Tt], b2[Tt], 0, 0, 0);
          b3[Tt] = __builtin_amdgcn_mfma_f32_16x16x32_bf16(th, uhl[c][Tt], b3[Tt], 0, 0, 0);
        }
      }

      if (quad < 2) {
#pragma unroll
        for (int Tt = 0; Tt < 2; ++Tt)
#pragma unroll
          for (int rr = 0; rr < 4; ++rr)
            scrB[par][wv][quad * 4 + rr][Tt * 16 + col16] =
                ah[Tt][rr] + b1[Tt][rr] + b2[Tt][rr] + b3[Tt][rr];
      }
      __syncthreads();

      float hsum = 0.f;
#pragma unroll
      for (int w2 = 0; w2 < NWAVE; ++w2) hsum += scrB[par][w2][wv][ecol];
      const float pre = hsum + bhv;
      const float e  = __expf(2.f * pre);
      const float hh = 1.f - 2.f / (e + 1.f);
      float hn = zvl * hreg + (1.f - zvl) * hh;
      hn = (mk > 0) ? hn : hreg;
      hreg = hn;

      if (lane < 32) {
        uint32_t* hdst = hb + ((size_t)((t + 1) & 1) * NGRP + g) * (GROWS * GDOUT)
                           + (size_t)wv * GDOUT + jb + lane;
        const uint32_t pv = pack_hl(hn);
        if (fast) st_pl(hdst, pv); else st_sc1(hdst, pv);
        if (t == GT - 1) out[(size_t)b_ep * GDOUT + jb + lane] = hn;
      }
      vm_drain();
      if (lane == 0) {
        if (fast) st_pl(hfl_my, (uint32_t)(t + 1)); else st_sc1(hfl_my, (uint32_t)(t + 1));
      }
    }
  }
}

extern "C" void kernel_launch(void* const* d_in, const int* in_sizes, int n_in,
                              void* d_out, int out_size, void* d_ws, size_t ws_size,
                              hipStream_t stream) {
  const float* X  = (const float*)d_in[0];
  const int* mask = (const int*)d_in[1];
  const float* Wz = (const float*)d_in[2];
  const float* Uz = (const float*)d_in[3];
  const float* bz = (const float*)d_in[4];
  const float* Wr = (const float*)d_in[5];
  const float* Ur = (const float*)d_in[6];
  const float* br = (const float*)d_in[7];
  const float* Wh = (const float*)d_in[8];
  const float* Uh = (const float*)d_in[9];
  const float* bh = (const float*)d_in[10];

  const int tagL = (ws_size >= (size_t)T_INIT_DW * 4) ? 1 : 0;
  hipMemsetAsync(d_ws, 0, (size_t)(tagL ? T_INIT_DW : C_INIT_DW) * 4, stream);

  hipLaunchKernelGGL(gru_fused, dim3(NWG), dim3(512), 0, stream,
                     X, mask, Wz, Uz, bz, Wr, Ur, br, Wh, Uh, bh,
                     (float*)d_out, (uint32_t*)d_ws, tagL);
}

// Round 5
// 2714.502 us; speedup vs baseline: 1.3321x; 1.3321x over previous
//
#include <hip/hip_runtime.h>
#include <stdint.h>

// GRU fused persistent kernel, MI355X gfx950 — round 13.
// History: r8 3.47ms (MALL sc1 flags) | r9 FAIL (plain buffer_inv = CU NOP) |
// r10 11.9ms (per-poll buffer_inv sc1 catastrophic) | r11 2.64ms WIN (nt-load
// flag polling, XCD-local L2 exchange; WRITE 147MB->2.3MB) | r12 3.62ms
// REGRESS (tag-in-payload poll = 8KB/wave/retry vs 2 lines -> L2 bandwidth
// self-jam; fast mode itself stayed correct).
//
// r13 = r11 protocol EXACTLY (flags + nt polls + plain stores, census+smoke
// + sc1 fallback) with latency-overlap surgery:
//  1. X/mask prefetch (t+1) issued right AFTER the rfl flag release: the
//     first rh-poll vmcnt absorbs X's ~900cy HBM latency CONCURRENTLY with
//     the rh round-trip -> X leaves the critical path. Issued after the
//     drain so the release is never delayed.
//  2. Phase-A slab split-issue: 4 slab loads issued, 8 x@W MFMAs (xa-only
//     deps) run under the L2 latency, then vmcnt(0)+sched_barrier(0)
//     (rule #18) before mk_frags/h-MFMAs.
//  3. 2-deep pipelined flag poll (fast path): two outstanding nt loads,
//     s_waitcnt vmcnt(1) -> detect latency ~halves. sched_barrier(0) after
//     each waitcnt pins the register reads (rule #18).
//  4. v_cvt_pk_bf16_f32 for xa conversion (8 inst vs ~64 VALU) and pack_hl.
//  Protocol/ordering proof unchanged from r11 (hardware-proven): producer
//  wave sets flag(t) only after its phase barrier (joins all 8 waves' slab
//  reads of t-1 inputs) and its own data stores drained (vmcnt0, L2 =
//  coherence point). Consumer post-barrier actions follow 8 waves' 16-flag
//  waits whose union = all 16 WGs -> rh (t+1 vs t) and h parity (t+2 vs t)
//  overwrites are safe. All spins budget-bounded; failures loud.
//
// ws (dwords): hb[2][8][8][512]=65536 | rhb[8][8][512]=32768 | hfl 8x512 |
// rfl 8x512 | census/smoke 160. Total 106656 dw = 427KB, all zeroed.

#define GT    512
#define GDIN  512
#define GDOUT 512
#define NGRP  8
#define NSL   16
#define GROWS 8
#define COLS  32
#define NWAVE 8
#define KW    64
#define NWG   (NGRP * NSL)                          // 128

#define OFF_HB    0
#define OFF_RHB   (2 * NGRP * GROWS * GDOUT)        // 65536
#define OFF_HFL   (OFF_RHB + NGRP * GROWS * GDOUT)  // 98304
#define FLSTR     4                                  // 16B per flag
#define FLGRP     (NSL * NWAVE * FLSTR)              // 512 dw per group
#define OFF_RFL   (OFF_HFL + NGRP * FLGRP)           // 102400
#define OFF_CNS   (OFF_RFL + NGRP * FLGRP)           // 106496
#define INIT_DW   (OFF_CNS + 160)                    // 106656 dw = 427KB

typedef __attribute__((ext_vector_type(8))) short bf16x8;
typedef __attribute__((ext_vector_type(4))) float f32x4;
typedef __attribute__((ext_vector_type(4))) unsigned int u32x4;

__device__ __forceinline__ short f2bf(float f) {
  union { float f; uint32_t u; } v; v.f = f;
  uint32_t r = (v.u + 0x7FFFu + ((v.u >> 16) & 1u)) >> 16;  // RNE
  return (short)(uint16_t)r;
}
__device__ __forceinline__ float bf2f(short s) {
  union { uint32_t u; float f; } v; v.u = ((uint32_t)(uint16_t)s) << 16;
  return v.f;
}
// pack f32 -> (bf16hi<<16)|bf16lo via 2x v_cvt_pk_bf16_f32
__device__ __forceinline__ uint32_t pack_hl(float v) {
  uint32_t t, o;
  asm("v_cvt_pk_bf16_f32 %0, %1, %1" : "=v"(t) : "v"(v));
  union { uint32_t u; float f; } hf; hf.u = t << 16;   // hi as f32
  float d = v - hf.f;
  asm("v_cvt_pk_bf16_f32 %0, %1, %2" : "=v"(o) : "v"(d), "v"(v));
  return o;                                            // [hi|lo]
}

__device__ __forceinline__ void st_sc1(uint32_t* p, uint32_t v) {
  asm volatile("global_store_dword %0, %1, off sc1" :: "v"(p), "v"(v) : "memory");
}
__device__ __forceinline__ void st_pl(uint32_t* p, uint32_t v) {
  asm volatile("global_store_dword %0, %1, off" :: "v"(p), "v"(v) : "memory");
}
__device__ __forceinline__ void vm_drain() {
  asm volatile("s_waitcnt vmcnt(0)" ::: "memory");
}
__device__ __forceinline__ void l1_inv() {   // one-time hygiene only (r10!)
  asm volatile("buffer_inv sc1" ::: "memory");
}
__device__ __forceinline__ uint32_t ld_nt(const uint32_t* p) {
  uint32_t v;
  asm volatile("global_load_dword %0, %1, off nt\n\ts_waitcnt vmcnt(0)"
               : "=v"(v) : "v"(p) : "memory");
  return v;
}

// issue-only slab (4x dwordx4, the wave's 16-dword A slab); wait separately
__device__ __forceinline__ void slab4_issue(const uint32_t* base, u32x4 d[4],
                                            int fast) {
  if (fast) {
    asm volatile(
      "global_load_dwordx4 %0, %4, off nt\n\t"
      "global_load_dwordx4 %1, %4, off offset:16 nt\n\t"
      "global_load_dwordx4 %2, %4, off offset:128 nt\n\t"
      "global_load_dwordx4 %3, %4, off offset:144 nt"
      : "=&v"(d[0]), "=&v"(d[1]), "=&v"(d[2]), "=&v"(d[3])
      : "v"(base) : "memory");
  } else {
    asm volatile(
      "global_load_dwordx4 %0, %4, off sc1\n\t"
      "global_load_dwordx4 %1, %4, off offset:16 sc1\n\t"
      "global_load_dwordx4 %2, %4, off offset:128 sc1\n\t"
      "global_load_dwordx4 %3, %4, off offset:144 sc1"
      : "=&v"(d[0]), "=&v"(d[1]), "=&v"(d[2]), "=&v"(d[3])
      : "v"(base) : "memory");
  }
}
__device__ __forceinline__ void slab_wait() {
  asm volatile("s_waitcnt vmcnt(0)" ::: "memory");
  __builtin_amdgcn_sched_barrier(0);     // rule #18: pin reads after waitcnt
}

// wave waits for its 2 producer WGs x 8 waves = 16 flags.
// FAST: 2-deep pipelined nt poll (two outstanding, vmcnt(1) waits older).
// SLOW: agent-scope load via MALL. Bounded: fail loud, never hang.
__device__ __forceinline__ void wait16(const uint32_t* fbase, uint32_t tgt,
                                       int lane, int wv, int fast, int& budget) {
  if (budget <= 0) return;
  const int idx = lane & 15;                       // lanes 16..63 duplicate
  const uint32_t* p = fbase +
      (size_t)(((2 * wv + (idx >> 3)) * NWAVE + (idx & 7)) * FLSTR);
  if (fast) {
    uint32_t v0, v1;
    asm volatile("global_load_dword %0, %1, off nt" : "=v"(v0) : "v"(p) : "memory");
    for (;;) {
      asm volatile("global_load_dword %0, %1, off nt" : "=v"(v1) : "v"(p) : "memory");
      asm volatile("s_waitcnt vmcnt(1)" ::: "memory");
      __builtin_amdgcn_sched_barrier(0);
      if (__all((int)(v0 >= tgt))) break;
      asm volatile("global_load_dword %0, %1, off nt" : "=v"(v0) : "v"(p) : "memory");
      asm volatile("s_waitcnt vmcnt(1)" ::: "memory");
      __builtin_amdgcn_sched_barrier(0);
      if (__all((int)(v1 >= tgt))) break;
      if ((budget -= 2) <= 0) break;
    }
    asm volatile("s_waitcnt vmcnt(0)" ::: "memory");  // quiesce stray poll
  } else {
    for (;;) {
      uint32_t v = __hip_atomic_load(p, __ATOMIC_RELAXED, __HIP_MEMORY_SCOPE_AGENT);
      if (__all((int)(v >= tgt))) break;
      if (--budget <= 0) break;
    }
  }
  asm volatile("" ::: "memory");
}

// 8 packed words -> hi/lo bf16x8 MFMA A-fragments (pure bit ops)
union U16x8 { uint32_t u[4]; bf16x8 v; };
__device__ __forceinline__ void mk_frags(const u32x4 A, const u32x4 B,
                                         bf16x8& hi, bf16x8& lo) {
  U16x8 h, l;
  h.u[0] = (A[0] >> 16) | (A[1] & 0xFFFF0000u);  l.u[0] = (A[0] & 0xFFFFu) | (A[1] << 16);
  h.u[1] = (A[2] >> 16) | (A[3] & 0xFFFF0000u);  l.u[1] = (A[2] & 0xFFFFu) | (A[3] << 16);
  h.u[2] = (B[0] >> 16) | (B[1] & 0xFFFF0000u);  l.u[2] = (B[0] & 0xFFFFu) | (B[1] << 16);
  h.u[3] = (B[2] >> 16) | (B[3] & 0xFFFF0000u);  l.u[3] = (B[2] & 0xFFFFu) | (B[3] << 16);
  hi = h.v; lo = l.v;
}
// f32x4 pair -> bf16x8 via 4x v_cvt_pk_bf16_f32
__device__ __forceinline__ bf16x8 cvt8(const f32x4 a, const f32x4 b) {
  U16x8 w;
  asm("v_cvt_pk_bf16_f32 %0, %1, %2" : "=v"(w.u[0]) : "v"(a[0]), "v"(a[1]));
  asm("v_cvt_pk_bf16_f32 %0, %1, %2" : "=v"(w.u[1]) : "v"(a[2]), "v"(a[3]));
  asm("v_cvt_pk_bf16_f32 %0, %1, %2" : "=v"(w.u[2]) : "v"(b[0]), "v"(b[1]));
  asm("v_cvt_pk_bf16_f32 %0, %1, %2" : "=v"(w.u[3]) : "v"(b[2]), "v"(b[3]));
  return w.v;
}

__global__ __launch_bounds__(512, 2)
void gru_fused(const float* __restrict__ X, const int* __restrict__ mask,
               const float* __restrict__ Wz, const float* __restrict__ Uz,
               const float* __restrict__ bz,
               const float* __restrict__ Wr, const float* __restrict__ Ur,
               const float* __restrict__ br,
               const float* __restrict__ Wh, const float* __restrict__ Uh,
               const float* __restrict__ bh,
               float* __restrict__ out, uint32_t* __restrict__ ws)
{
  const int tid   = threadIdx.x;
  const int wv    = tid >> 6;
  const int lane  = tid & 63;
  const int col16 = lane & 15;
  const int quad  = lane >> 4;
  const int row8  = lane & 7;

  // ---- census (assignment) + smoke test (fast/slow selection) ----
  uint32_t* cns = ws + OFF_CNS;
  __shared__ int s_mode, s_g, s_sl;
  if (tid == 0) {
    uint32_t xcc = 0;
    asm volatile("s_getreg_b32 %0, hwreg(HW_REG_XCC_ID)" : "=s"(xcc));
    xcc &= 7u;
    uint32_t slot = __hip_atomic_fetch_add(&cns[xcc], 1u, __ATOMIC_RELAXED,
                                           __HIP_MEMORY_SCOPE_AGENT);
    if (slot >= (uint32_t)NSL)
      __hip_atomic_fetch_add(&cns[9], 1u, __ATOMIC_RELAXED, __HIP_MEMORY_SCOPE_AGENT);
    __hip_atomic_fetch_add(&cns[8], 1u, __ATOMIC_RELEASE, __HIP_MEMORY_SCOPE_AGENT);
    uint32_t tv = 0; long sp = 0;
    do {
      tv = __hip_atomic_load(&cns[8], __ATOMIC_ACQUIRE, __HIP_MEMORY_SCOPE_AGENT);
    } while (tv < (uint32_t)NWG && ++sp < 2000000L);
    uint32_t bad = __hip_atomic_load(&cns[9], __ATOMIC_RELAXED, __HIP_MEMORY_SCOPE_AGENT);
    const int cok = (tv >= (uint32_t)NWG && bad == 0u);
    int g_, sl_, mode_ = 0;
    if (cok) {
      g_ = (int)xcc; sl_ = (int)slot;
      l1_inv();
      uint32_t* tok = cns + 16;
      st_pl(&tok[g_ * NSL + sl_], 1u);
      vm_drain();
      const uint32_t* np = &tok[g_ * NSL + ((sl_ + 1) & (NSL - 1))];
      int ok = 0;
      for (long i = 0; i < 300000L; ++i) {
        if (ld_nt(np) != 0u) { ok = 1; break; }
      }
      if (!ok)
        __hip_atomic_fetch_add(&cns[11], 1u, __ATOMIC_RELAXED, __HIP_MEMORY_SCOPE_AGENT);
      __hip_atomic_fetch_add(&cns[10], 1u, __ATOMIC_RELEASE, __HIP_MEMORY_SCOPE_AGENT);
      uint32_t tv2 = 0; sp = 0;
      do {
        tv2 = __hip_atomic_load(&cns[10], __ATOMIC_ACQUIRE, __HIP_MEMORY_SCOPE_AGENT);
      } while (tv2 < (uint32_t)NWG && ++sp < 2000000L);
      uint32_t fl = __hip_atomic_load(&cns[11], __ATOMIC_RELAXED, __HIP_MEMORY_SCOPE_AGENT);
      mode_ = (tv2 >= (uint32_t)NWG && fl == 0u) ? 1 : 0;
    } else {
      g_ = (int)(blockIdx.x & 7); sl_ = (int)(blockIdx.x >> 3);
    }
    s_mode = mode_; s_g = g_; s_sl = sl_;
  }
  __syncthreads();
  const int fast = __builtin_amdgcn_readfirstlane(s_mode);
  const int g    = __builtin_amdgcn_readfirstlane(s_g);
  const int sl   = __builtin_amdgcn_readfirstlane(s_sl);
  l1_inv();                            // one-time: clear cross-launch vL1

  const int jb = sl * COLS;
  const int kb = wv * KW;

  uint32_t* hb  = ws + OFF_HB;
  uint32_t* rhb = ws + OFF_RHB;
  uint32_t* hfl = ws + OFF_HFL + (size_t)g * FLGRP;
  uint32_t* rfl = ws + OFF_RFL + (size_t)g * FLGRP;
  uint32_t* hfl_my = hfl + (size_t)(sl * NWAVE + wv) * FLSTR;
  uint32_t* rfl_my = rfl + (size_t)(sl * NWAVE + wv) * FLSTR;
  uint32_t* rhg = rhb + (size_t)g * (GROWS * GDOUT);
  const int slab_off = row8 * GDOUT + kb + quad * 8;

  __shared__ __align__(16) float scrA[2][NWAVE][2][GROWS][COLS];  // 32KB
  __shared__ __align__(16) float scrB[2][NWAVE][GROWS][COLS];     // 16KB

  // ---------- one-time: weight B-fragments into registers ----------
  bf16x8 uzh[2][2], uzl[2][2], urh[2][2], url[2][2], uhh[2][2], uhl[2][2];
  bf16x8 wzf[2][2], wrf[2][2], whf[2][2];
#pragma unroll
  for (int c = 0; c < 2; ++c) {
#pragma unroll
    for (int Tt = 0; Tt < 2; ++Tt) {
      const int k0 = kb + c * 32 + quad * 8;
      const int j  = jb + Tt * 16 + col16;
      bf16x8 t_uzh, t_uzl, t_urh, t_url, t_uhh, t_uhl, t_wz, t_wr, t_wh;
#pragma unroll
      for (int i = 0; i < 8; ++i) {
        const int idx = (k0 + i) * GDOUT + j;
        float u; short hi;
        u = Uz[idx]; hi = f2bf(u); t_uzh[i] = hi; t_uzl[i] = f2bf(u - bf2f(hi));
        u = Ur[idx]; hi = f2bf(u); t_urh[i] = hi; t_url[i] = f2bf(u - bf2f(hi));
        u = Uh[idx]; hi = f2bf(u); t_uhh[i] = hi; t_uhl[i] = f2bf(u - bf2f(hi));
        t_wz[i] = f2bf(Wz[idx]);
        t_wr[i] = f2bf(Wr[idx]);
        t_wh[i] = f2bf(Wh[idx]);
      }
      uzh[c][Tt] = t_uzh; uzl[c][Tt] = t_uzl; urh[c][Tt] = t_urh; url[c][Tt] = t_url;
      uhh[c][Tt] = t_uhh; uhl[c][Tt] = t_uhl;
      wzf[c][Tt] = t_wz;  wrf[c][Tt] = t_wr;  whf[c][Tt] = t_wh;
    }
  }

  const int ecol = lane & 31;
  const float bzv = bz[jb + ecol];
  const float brv = br[jb + ecol];
  const float bhv = bh[jb + ecol];
  const int b_ep = GROWS * g + wv;

  float hreg = 0.f;
  float zvl  = 0.f;
  int budget = 4000000;

  // ---- X/mask prefetch registers (t = 0) ----
  f32x4 xpA[2], xpB[2]; int mkpre;
  {
    const float* xr = X + (size_t)(GROWS * g + row8) * GT * GDIN;
#pragma unroll
    for (int c = 0; c < 2; ++c) {
      const float* xp = xr + kb + c * 32 + quad * 8;
      xpA[c] = *(const f32x4*)xp;
      xpB[c] = *(const f32x4*)(xp + 4);
    }
    mkpre = mask[(size_t)b_ep * GT + 0];
  }

  for (int t = 0; t < GT; ++t) {
    const int par = t & 1;
    // xa from prefetched regs: 8x v_cvt_pk (no vmem on critical path)
    bf16x8 xa[2];
#pragma unroll
    for (int c = 0; c < 2; ++c) xa[c] = cvt8(xpA[c], xpB[c]);
    const int mk = mkpre;

    // ---- phase A: wait h(t) flags, split-issue slab, x@W under latency ----
    if (t) wait16(hfl, (uint32_t)t, lane, wv, fast, budget);
    const uint32_t* hsrc = hb + ((size_t)par * NGRP + g) * (GROWS * GDOUT) + slab_off;
    u32x4 hd[4];
    slab4_issue(hsrc, hd, fast);

    f32x4 az[2]  = {{0,0,0,0},{0,0,0,0}}, az2[2] = {{0,0,0,0},{0,0,0,0}};
    f32x4 ar[2]  = {{0,0,0,0},{0,0,0,0}}, ar2[2] = {{0,0,0,0},{0,0,0,0}};
    // x@W MFMAs overlap the slab L2 latency (xa-only deps)
#pragma unroll
    for (int c = 0; c < 2; ++c)
#pragma unroll
      for (int Tt = 0; Tt < 2; ++Tt) {
        az2[Tt] = __builtin_amdgcn_mfma_f32_16x16x32_bf16(xa[c], wzf[c][Tt], az2[Tt], 0, 0, 0);
        ar2[Tt] = __builtin_amdgcn_mfma_f32_16x16x32_bf16(xa[c], wrf[c][Tt], ar2[Tt], 0, 0, 0);
      }
    slab_wait();                          // vmcnt(0) + sched_barrier (rule #18)

#pragma unroll
    for (int c = 0; c < 2; ++c) {
      bf16x8 hhi, hlo;
      mk_frags(hd[2 * c], hd[2 * c + 1], hhi, hlo);
#pragma unroll
      for (int Tt = 0; Tt < 2; ++Tt) {
        az[Tt]  = __builtin_amdgcn_mfma_f32_16x16x32_bf16(hhi, uzh[c][Tt], az[Tt],  0, 0, 0);
        az2[Tt] = __builtin_amdgcn_mfma_f32_16x16x32_bf16(hlo, uzh[c][Tt], az2[Tt], 0, 0, 0);
        az[Tt]  = __builtin_amdgcn_mfma_f32_16x16x32_bf16(hhi, uzl[c][Tt], az[Tt],  0, 0, 0);
        ar[Tt]  = __builtin_amdgcn_mfma_f32_16x16x32_bf16(hhi, urh[c][Tt], ar[Tt],  0, 0, 0);
        ar2[Tt] = __builtin_amdgcn_mfma_f32_16x16x32_bf16(hlo, urh[c][Tt], ar2[Tt], 0, 0, 0);
        ar[Tt]  = __builtin_amdgcn_mfma_f32_16x16x32_bf16(hhi, url[c][Tt], ar[Tt],  0, 0, 0);
      }
    }

    // ---- distributed reduce + per-wave rh release (1 barrier) ----
    if (quad < 2) {
#pragma unroll
      for (int Tt = 0; Tt < 2; ++Tt)
#pragma unroll
        for (int rr = 0; rr < 4; ++rr) {
          scrA[par][wv][0][quad * 4 + rr][Tt * 16 + col16] = az[Tt][rr] + az2[Tt][rr];
          scrA[par][wv][1][quad * 4 + rr][Tt * 16 + col16] = ar[Tt][rr] + ar2[Tt][rr];
        }
    }
    __syncthreads();                     // joins all 8 waves' h-waits

    float zsum = 0.f, rsum = 0.f;
#pragma unroll
    for (int w2 = 0; w2 < NWAVE; ++w2) {
      zsum += scrA[par][w2][0][wv][ecol];
      rsum += scrA[par][w2][1][wv][ecol];
    }
    zvl = 1.f / (1.f + __expf(-(zsum + bzv)));
    const float rvl = 1.f / (1.f + __expf(-(rsum + brv)));
    if (lane < 32) {
      uint32_t* dst = rhg + (size_t)wv * GDOUT + jb + lane;
      const uint32_t pv = pack_hl(rvl * hreg);
      if (fast) st_pl(dst, pv); else st_sc1(dst, pv);
    }
    vm_drain();                          // only rh stores outstanding: fast
    if (lane == 0) {
      if (fast) st_pl(rfl_my, (uint32_t)(t + 1)); else st_sc1(rfl_my, (uint32_t)(t + 1));
    }

    // ---- rh-RTT shadow: X(t+1)/mask prefetch issue + ah MFMAs ----
    // The first rh-poll vmcnt absorbs X latency CONCURRENT with the RTT.
    {
      const int tn = (t + 1 < GT) ? t + 1 : t;
      const float* xr = X + ((size_t)(GROWS * g + row8) * GT + tn) * GDIN;
#pragma unroll
      for (int c = 0; c < 2; ++c) {
        const float* xp = xr + kb + c * 32 + quad * 8;
        xpA[c] = *(const f32x4*)xp;
        xpB[c] = *(const f32x4*)(xp + 4);
      }
      mkpre = mask[(size_t)b_ep * GT + tn];
    }
    f32x4 ah[2] = {{0,0,0,0},{0,0,0,0}};
#pragma unroll
    for (int c = 0; c < 2; ++c)
#pragma unroll
      for (int Tt = 0; Tt < 2; ++Tt)
        ah[Tt] = __builtin_amdgcn_mfma_f32_16x16x32_bf16(xa[c], whf[c][Tt], ah[Tt], 0, 0, 0);

    // ---- phase B: wait rh(t), slab, 12 MFMAs (Uh) ----
    wait16(rfl, (uint32_t)(t + 1), lane, wv, fast, budget);
    u32x4 rd[4];
    slab4_issue(rhg + slab_off, rd, fast);
    slab_wait();

    f32x4 b1[2] = {{0,0,0,0},{0,0,0,0}}, b2[2] = {{0,0,0,0},{0,0,0,0}};
    f32x4 b3[2] = {{0,0,0,0},{0,0,0,0}};
#pragma unroll
    for (int c = 0; c < 2; ++c) {
      bf16x8 th, tl;
      mk_frags(rd[2 * c], rd[2 * c + 1], th, tl);
#pragma unroll
      for (int Tt = 0; Tt < 2; ++Tt) {
        b1[Tt] = __builtin_amdgcn_mfma_f32_16x16x32_bf16(th, uhh[c][Tt], b1[Tt], 0, 0, 0);
        b2[Tt] = __builtin_amdgcn_mfma_f32_16x16x32_bf16(tl, uhh[c][Tt], b2[Tt], 0, 0, 0);
        b3[Tt] = __builtin_amdgcn_mfma_f32_16x16x32_bf16(th, uhl[c][Tt], b3[Tt], 0, 0, 0);
      }
    }

    if (quad < 2) {
#pragma unroll
      for (int Tt = 0; Tt < 2; ++Tt)
#pragma unroll
        for (int rr = 0; rr < 4; ++rr)
          scrB[par][wv][quad * 4 + rr][Tt * 16 + col16] =
              ah[Tt][rr] + b1[Tt][rr] + b2[Tt][rr] + b3[Tt][rr];
    }
    __syncthreads();                     // joins all 8 waves' rh-waits

    float hsum = 0.f;
#pragma unroll
    for (int w2 = 0; w2 < NWAVE; ++w2) hsum += scrB[par][w2][wv][ecol];
    const float pre = hsum + bhv;
    const float e  = __expf(2.f * pre);  // tanh, saturation-safe
    const float hh = 1.f - 2.f / (e + 1.f);
    float hn = zvl * hreg + (1.f - zvl) * hh;
    hn = (mk > 0) ? hn : hreg;
    hreg = hn;

    if (lane < 32) {
      uint32_t* hdst = hb + ((size_t)((t + 1) & 1) * NGRP + g) * (GROWS * GDOUT)
                         + (size_t)wv * GDOUT + jb + lane;
      const uint32_t pv = pack_hl(hn);
      if (fast) st_pl(hdst, pv); else st_sc1(hdst, pv);
      if (t == GT - 1) out[(size_t)b_ep * GDOUT + jb + lane] = hn;
    }
    vm_drain();                          // X prefetch long done; h stores ack
    if (lane == 0) {
      if (fast) st_pl(hfl_my, (uint32_t)(t + 1)); else st_sc1(hfl_my, (uint32_t)(t + 1));
    }
  }
}

extern "C" void kernel_launch(void* const* d_in, const int* in_sizes, int n_in,
                              void* d_out, int out_size, void* d_ws, size_t ws_size,
                              hipStream_t stream) {
  const float* X  = (const float*)d_in[0];
  const int* mask = (const int*)d_in[1];
  const float* Wz = (const float*)d_in[2];
  const float* Uz = (const float*)d_in[3];
  const float* bz = (const float*)d_in[4];
  const float* Wr = (const float*)d_in[5];
  const float* Ur = (const float*)d_in[6];
  const float* br = (const float*)d_in[7];
  const float* Wh = (const float*)d_in[8];
  const float* Uh = (const float*)d_in[9];
  const float* bh = (const float*)d_in[10];

  hipMemsetAsync(d_ws, 0, (size_t)INIT_DW * 4, stream);

  hipLaunchKernelGGL(gru_fused, dim3(NWG), dim3(512), 0, stream,
                     X, mask, Wz, Uz, bz, Wr, Ur, br, Wh, Uh, bh,
                     (float*)d_out, (uint32_t*)d_ws);
}